// Round 8
// baseline (220.668 us; speedup 1.0000x reference)
//
#include <hip/hip_runtime.h>
#include <hip/hip_bf16.h>

typedef unsigned short ushort_t;
typedef __attribute__((ext_vector_type(8))) short s8;     // 8 bf16 (4 VGPRs)
typedef __attribute__((ext_vector_type(4))) float f4;     // 16x16 MFMA C/D

__device__ __forceinline__ unsigned short f2bf(float f) {
  union { float f; unsigned int u; } c; c.f = f;
  unsigned int r = (c.u + 0x7fffu + ((c.u >> 16) & 1u)) >> 16;
  return (unsigned short)r;
}
__device__ __forceinline__ float bf2f(ushort_t u) {
  union { unsigned int i; float f; } c; c.i = ((unsigned int)u) << 16; return c.f;
}
__device__ __forceinline__ uint4 pack8(float4 a, float4 b) {
  uint4 r;
  r.x = (unsigned)f2bf(a.x) | ((unsigned)f2bf(a.y) << 16);
  r.y = (unsigned)f2bf(a.z) | ((unsigned)f2bf(a.w) << 16);
  r.z = (unsigned)f2bf(b.x) | ((unsigned)f2bf(b.y) << 16);
  r.w = (unsigned)f2bf(b.z) | ((unsigned)f2bf(b.w) << 16);
  return r;
}
// raw v_sqrt_f32 / v_exp_f32 (~1 ulp) — avoid libm expansions
__device__ __forceinline__ float fsqrt_fast(float x) {
  float r; asm("v_sqrt_f32 %0, %1" : "=v"(r) : "v"(x)); return r;
}
__device__ __forceinline__ float fexp2_fast(float x) {
  float r; asm("v_exp_f32 %0, %1" : "=v"(r) : "v"(x)); return r;
}
// global -> LDS DMA, 16B per lane, wave-uniform LDS base + lane*16
// NOTE (R6 lesson): only profitable with coalesced lane addressing AND a
// pipeline to hide the latency (k_attn). NOT a drop-in for 2-barrier GEMMs.
__device__ __forceinline__ void dma16(const ushort_t* g, const short* l) {
  __builtin_amdgcn_global_load_lds(
      (const __attribute__((address_space(1))) unsigned int*)g,
      (__attribute__((address_space(3))) unsigned int*)(unsigned long)l,
      16, 0, 0);
}

#define LOG2E 1.44269504f

// ---- all weight transposes + mask staging in one launch ----
// y 0..4: dst[n][k] = bf16(src[k][n]); y==5: mask -> float weights + zero acc
__global__ __launch_bounds__(256) void k_wt_all(
    const float* __restrict__ enc_w, const float* __restrict__ wq,
    const float* __restrict__ wk, const float* __restrict__ wv,
    const float* __restrict__ bn_w, const int* __restrict__ mask,
    ushort_t* __restrict__ enc_wT, ushort_t* __restrict__ wqkvT,
    ushort_t* __restrict__ bn_wT, float* __restrict__ pooledAcc) {
  const int y = blockIdx.y;
  const int i = blockIdx.x * 256 + threadIdx.x;
  if (y == 0) {
    if (i < 131072) { const int n = i >> 9, k = i & 511; enc_wT[i] = f2bf(enc_w[k * 256 + n]); }
  } else if (y <= 3) {
    if (i < 65536) {
      const int n = i >> 8, k = i & 255;
      const float* src = (y == 1) ? wq : (y == 2) ? wk : wv;
      wqkvT[(y - 1) * 65536 + i] = f2bf(src[k * 256 + n]);
    }
  } else if (y == 4) {
    if (i < 32768) { const int n = i >> 8, k = i & 255; bn_wT[i] = f2bf(bn_w[k * 128 + n]); }
  } else {
    if (i < 16384) pooledAcc[1024 + i] = mask[i] ? 0.f : 1.f;
    if (i < 1024) pooledAcc[i] = 0.f;
  }
}

// ---- FUSED encoder GEMM+LN+ReLU  ->  QKV GEMM (h never leaves the block) ----
// 32-row blocks (grid 512 = 2/CU). Phase 1 = R5-proven enc body, epilogue
// writes h to LDS hl[32][264] (528B row stride == proven 72-short pad mod 32
// banks) instead of global. Phase 2 = R7-proven qkv loop, A-frags read from
// hl (no A staging, no h HBM round-trip), 3 types sharing the Bl buffer.
// Saves: 8MB h write + 24MB h re-read + one kernel launch/drain.
// v -> vt with the R3-proven PV key permutation: block = one 32-key chunk,
// key (wm*16 + quad*4 + r) -> slot (quad*8 + wm*4 + r).
__global__ __launch_bounds__(256, 2) void k_enc_qkv(
    const float* __restrict__ A, const ushort_t* __restrict__ WT,
    const float* __restrict__ bia, const float* __restrict__ g,
    const float* __restrict__ beta,
    const ushort_t* __restrict__ WQKV,
    const float* __restrict__ bq, const float* __restrict__ bk,
    const float* __restrict__ bv,
    ushort_t* __restrict__ q, ushort_t* __restrict__ kko, ushort_t* __restrict__ vt) {
  __shared__ short Al[32 * 72];
  __shared__ short Bl[256 * 72];
  __shared__ short hl[32 * 264];             // 16.5 KB, bf16 h rows (pad 264)
  __shared__ float red1[32][2], red2[32][2];
  const int t = threadIdx.x;
  const int wv = t >> 6, lane = t & 63, l16 = lane & 15, quad = lane >> 4;
  const int wm = wv >> 1, wn = wv & 1;
  const int row0 = blockIdx.x * 32;

  // ================= phase 1: enc GEMM + LN + ReLU -> hl =================
  {
    f4 acc[8];
#pragma unroll
    for (int nf = 0; nf < 8; ++nf) acc[nf] = (f4){0.f, 0.f, 0.f, 0.f};

    for (int k0 = 0; k0 < 512; k0 += 64) {
      __syncthreads();
      {
        const int r = t >> 3, c8 = t & 7;
        const float* src = &A[(size_t)(row0 + r) * 512 + k0 + c8 * 8];
        *(uint4*)&Al[r * 72 + c8 * 8] =
            pack8(*(const float4*)src, *(const float4*)(src + 4));
      }
#pragma unroll
      for (int i = 0; i < 8; ++i) {
        const int ch = t + i * 256;
        const int r = ch >> 3, c8 = ch & 7;
        *(uint4*)&Bl[r * 72 + c8 * 8] =
            *(const uint4*)&WT[(size_t)r * 512 + k0 + c8 * 8];
      }
      __syncthreads();
#pragma unroll
      for (int kc = 0; kc < 2; ++kc) {
        const s8 af = *(const s8*)&Al[(wm * 16 + l16) * 72 + kc * 32 + quad * 8];
#pragma unroll
        for (int nf = 0; nf < 8; ++nf) {
          const s8 bf = *(const s8*)&Bl[(wn * 128 + nf * 16 + l16) * 72 + kc * 32 + quad * 8];
          acc[nf] = __builtin_amdgcn_mfma_f32_16x16x32_bf16(af, bf, acc[nf], 0, 0, 0);
        }
      }
    }
    float bi[8], gg[8], bb[8];
#pragma unroll
    for (int nf = 0; nf < 8; ++nf) {
      const int col = wn * 128 + nf * 16 + l16;
      bi[nf] = bia[col]; gg[nf] = g[col]; bb[nf] = beta[col];
    }
    float s1[4] = {0.f, 0.f, 0.f, 0.f}, s2[4] = {0.f, 0.f, 0.f, 0.f};
#pragma unroll
    for (int nf = 0; nf < 8; ++nf)
#pragma unroll
      for (int r = 0; r < 4; ++r) {
        const float v = acc[nf][r] + bi[nf];
        acc[nf][r] = v;
        s1[r] += v; s2[r] += v * v;
      }
#pragma unroll
    for (int m = 1; m < 16; m <<= 1) {
#pragma unroll
      for (int r = 0; r < 4; ++r) {
        s1[r] += __shfl_xor(s1[r], m);
        s2[r] += __shfl_xor(s2[r], m);
      }
    }
    if (l16 == 0) {
#pragma unroll
      for (int r = 0; r < 4; ++r) {
        const int rl = wm * 16 + quad * 4 + r;
        red1[rl][wn] = s1[r]; red2[rl][wn] = s2[r];
      }
    }
    __syncthreads();
#pragma unroll
    for (int r = 0; r < 4; ++r) {
      const int rl = wm * 16 + quad * 4 + r;
      const float mu = (red1[rl][0] + red1[rl][1]) * (1.f / 256.f);
      const float var = (red2[rl][0] + red2[rl][1]) * (1.f / 256.f) - mu * mu;
      const float rstd = rsqrtf(var + 1e-5f);
#pragma unroll
      for (int nf = 0; nf < 8; ++nf) {
        const int col = wn * 128 + nf * 16 + l16;
        const float v = (acc[nf][r] - mu) * rstd * gg[nf] + bb[nf];
        hl[rl * 264 + col] = (short)f2bf(fmaxf(v, 0.f));
      }
    }
  }
  // (phase 2's first barrier makes hl + Bl reuse safe)

  // ================= phase 2: QKV GEMM from hl =================
  const int b = row0 >> 11;
  for (int type = 0; type < 3; ++type) {
    const ushort_t* wtb = WQKV + (size_t)type * 65536;
    f4 acc[8];
#pragma unroll
    for (int nf = 0; nf < 8; ++nf) acc[nf] = (f4){0.f, 0.f, 0.f, 0.f};

    for (int k0 = 0; k0 < 256; k0 += 64) {
      __syncthreads();
#pragma unroll
      for (int i = 0; i < 8; ++i) {
        const int ch = t + i * 256;
        const int r = ch >> 3, c8 = ch & 7;
        *(uint4*)&Bl[r * 72 + c8 * 8] =
            *(const uint4*)&wtb[(size_t)r * 256 + k0 + c8 * 8];
      }
      __syncthreads();
#pragma unroll
      for (int kc = 0; kc < 2; ++kc) {
        const s8 af = *(const s8*)&hl[(wm * 16 + l16) * 264 + k0 + kc * 32 + quad * 8];
#pragma unroll
        for (int nf = 0; nf < 8; ++nf) {
          const s8 bf = *(const s8*)&Bl[(wn * 128 + nf * 16 + l16) * 72 + kc * 32 + quad * 8];
          acc[nf] = __builtin_amdgcn_mfma_f32_16x16x32_bf16(af, bf, acc[nf], 0, 0, 0);
        }
      }
    }
    const float* bias = (type == 0) ? bq : (type == 1) ? bk : bv;
    if (type == 2) {
#pragma unroll
      for (int nf = 0; nf < 8; ++nf) {
        const int col = wn * 128 + nf * 16 + l16;
        const float bi = bias[col];
        // chunk-local key (wm*16 + quad*4 + r) -> permuted slot (quad*8 + wm*4 + r)
        const int n = (row0 & 2047) + quad * 8 + wm * 4;
        ushort4 pk;
        pk.x = f2bf(acc[nf][0] + bi);
        pk.y = f2bf(acc[nf][1] + bi);
        pk.z = f2bf(acc[nf][2] + bi);
        pk.w = f2bf(acc[nf][3] + bi);
        *(ushort4*)&vt[((size_t)b * 256 + col) * 2048 + n] = pk;
      }
    } else {
      ushort_t* dst = (type == 0) ? q : kko;
      const float sc = (type == 0) ? (0.0625f * LOG2E) : 1.f;  // fold log2e for exp2
#pragma unroll
      for (int nf = 0; nf < 8; ++nf) {
        const int col = wn * 128 + nf * 16 + l16;
        const float bi = bias[col];
#pragma unroll
        for (int r = 0; r < 4; ++r) {
          const int row = row0 + wm * 16 + quad * 4 + r;
          dst[(size_t)row * 256 + col] = f2bf((acc[nf][r] + bi) * sc);
        }
      }
    }
  }
}

// ---- MFMA flash attention, 8-wave / 32q-per-wave, pipelined DMA version ----
// (R5-proven, byte-identical) grid (8,4,8) = 256 blocks (1/CU), 512 thr.
// Triple-buffered LDS, DMAs 2 tiles ahead, counted s_waitcnt vmcnt(4) before
// a raw s_barrier so the next tile's DMAs stay in flight across the barrier.
__global__ __launch_bounds__(512, 2) void k_attn(
    const ushort_t* __restrict__ qb, const ushort_t* __restrict__ kb,
    const ushort_t* __restrict__ vtb,
    const float* __restrict__ coords, const int* __restrict__ mask,
    const float* __restrict__ gam,
    ushort_t* __restrict__ Opb, float* __restrict__ lws) {
  __shared__ short kld[3][8192];             // 3 x 16 KB, [d-group:32][key:32][8]
  __shared__ short vld[3][8192];             // 3 x 16 KB, [slot-group:4][d:256][8]
  __shared__ __align__(16) float2 cls[512];  // key coords (4 KB)
  __shared__ __align__(16) float  mls[512];  // key mask weight 0/1 (2 KB)
  const int t = threadIdx.x;
  const int wv = t >> 6, lane = t & 63, l16 = lane & 15, quad = lane >> 4;
  const int b = blockIdx.z, ks = blockIdx.y;
  const int qw = blockIdx.x * 256 + wv * 32;
  const int kbase = ks * 512;

  const ushort_t* kbb = kb + ((size_t)b * 2048 + kbase) * 256;
  const ushort_t* vbb = vtb + (size_t)b * 256 * 2048 + kbase;

  // stage tile tt into buffer ib (4 dma16/thread, issued in fixed order)
  auto stage = [&](int tt, int ib) {
    const ushort_t* kn = kbb + (size_t)tt * 8192;
    const ushort_t* vn = vbb + tt * 32;
    const int key = t & 31, dg = t >> 5;
    dma16(kn + (size_t)key * 256 + dg * 8, &kld[ib][t * 8]);
    dma16(kn + (size_t)key * 256 + dg * 8 + 128, &kld[ib][(t + 512) * 8]);
    const int d = t & 255, kg = t >> 8;
    dma16(vn + (size_t)d * 2048 + kg * 8, &vld[ib][t * 8]);
    dma16(vn + (size_t)d * 2048 + kg * 8 + 16, &vld[ib][(t + 512) * 8]);
  };

  // ---- prologue: stage tiles 0,1; stage coords/mask; load per-wave consts ----
  stage(0, 0);
  stage(1, 1);
  cls[t] = ((const float2*)coords)[b * 2048 + kbase + t];
  mls[t] = mask[b * 2048 + kbase + t] ? 0.f : 1.f;

  s8 qa[2][8];
  {
    const ushort_t* qrow = qb + ((size_t)b * 2048 + qw + l16) * 256 + quad * 8;
#pragma unroll
    for (int c = 0; c < 8; ++c) {
      qa[0][c] = *(const s8*)(qrow + c * 32);
      qa[1][c] = *(const s8*)(qrow + 16 * 256 + c * 32);
    }
  }
  float rcx[2], rcy[2];
  {
    const float2 c0 = ((const float2*)coords)[b * 2048 + qw + l16];
    const float2 c1 = ((const float2*)coords)[b * 2048 + qw + 16 + l16];
    rcx[0] = c0.x; rcy[0] = c0.y; rcx[1] = c1.x; rcy[1] = c1.y;
  }
  const float gl2 = fabsf(gam[0]) * LOG2E;

  f4 o[2][16];
#pragma unroll
  for (int h = 0; h < 2; ++h)
#pragma unroll
    for (int dt = 0; dt < 16; ++dt) o[h][dt] = (f4){0.f, 0.f, 0.f, 0.f};
  float lrun[2] = {0.f, 0.f};

  // per-tile compute on buffers kldc/vldc
  auto compute_tile = [&](int kt, const short* kldc, const short* vldc) {
    // QK^T swapped: sc[h][s] = K(s-frag) x Q(half h); each kf feeds both halves
    f4 sc[2][2];
    sc[0][0] = (f4){0.f, 0.f, 0.f, 0.f}; sc[0][1] = (f4){0.f, 0.f, 0.f, 0.f};
    sc[1][0] = (f4){0.f, 0.f, 0.f, 0.f}; sc[1][1] = (f4){0.f, 0.f, 0.f, 0.f};
#pragma unroll
    for (int c = 0; c < 8; ++c) {
      const s8 kf0 = *(const s8*)&kldc[((c * 4 + quad) * 32 + l16) * 8];
      sc[0][0] = __builtin_amdgcn_mfma_f32_16x16x32_bf16(kf0, qa[0][c], sc[0][0], 0, 0, 0);
      sc[1][0] = __builtin_amdgcn_mfma_f32_16x16x32_bf16(kf0, qa[1][c], sc[1][0], 0, 0, 0);
      const s8 kf1 = *(const s8*)&kldc[((c * 4 + quad) * 32 + 16 + l16) * 8];
      sc[0][1] = __builtin_amdgcn_mfma_f32_16x16x32_bf16(kf1, qa[0][c], sc[0][1], 0, 0, 0);
      sc[1][1] = __builtin_amdgcn_mfma_f32_16x16x32_bf16(kf1, qa[1][c], sc[1][1], 0, 0, 0);
    }
    // softmax weights in-register (no max-shift); coords/mask broadcast from LDS
    s8 paf[2];
#pragma unroll
    for (int h = 0; h < 2; ++h) {
      unsigned pu[4];
#pragma unroll
      for (int s = 0; s < 2; ++s) {
        const int k0 = kt * 32 + s * 16 + quad * 4;
        const float4 c01 = *(const float4*)&cls[k0];
        const float4 c23 = *(const float4*)&cls[k0 + 2];
        const float4 mm = *(const float4*)&mls[k0];
        const float kx[4] = {c01.x, c01.z, c23.x, c23.z};
        const float ky[4] = {c01.y, c01.w, c23.y, c23.w};
        const float mv[4] = {mm.x, mm.y, mm.z, mm.w};
        float w[4];
#pragma unroll
        for (int r = 0; r < 4; ++r) {
          const float p = fexp2_fast(sc[h][s][r]);   // q pre-scaled by log2e/16
          lrun[h] += p;
          const float dx = rcx[h] - kx[r], dy = rcy[h] - ky[r];
          const float dist = fsqrt_fast(dx * dx + dy * dy);
          w[r] = p * fexp2_fast(-gl2 * dist) * mv[r];
        }
        pu[s * 2 + 0] = (unsigned)f2bf(w[0]) | ((unsigned)f2bf(w[1]) << 16);
        pu[s * 2 + 1] = (unsigned)f2bf(w[2]) | ((unsigned)f2bf(w[3]) << 16);
      }
      union { s8 v; unsigned u[4]; } cv;
      cv.u[0] = pu[0]; cv.u[1] = pu[1]; cv.u[2] = pu[2]; cv.u[3] = pu[3];
      paf[h] = cv.v;
    }
    // PV (16x16x32): one aligned conflict-free b128 per dt, shared by halves
#pragma unroll
    for (int dt = 0; dt < 16; ++dt) {
      const s8 bvf = *(const s8*)&vldc[(quad * 256 + dt * 16 + l16) * 8];
      o[0][dt] = __builtin_amdgcn_mfma_f32_16x16x32_bf16(paf[0], bvf, o[0][dt], 0, 0, 0);
      o[1][dt] = __builtin_amdgcn_mfma_f32_16x16x32_bf16(paf[1], bvf, o[1][dt], 0, 0, 0);
    }
  };

  __syncthreads();              // full drain: tiles 0,1 + cls/mls visible
  stage(2, 2);                  // tile 2 in flight during tile 0 compute
  compute_tile(0, kld[0], vld[0]);

  int cur = 1;                  // buffer of tile kt
  for (int kt = 1; kt < 15; ++kt) {
    // tile kt's DMAs are the 4 oldest of (up to) 8 outstanding; kt+1's stay in flight
    asm volatile("s_waitcnt vmcnt(4)" ::: "memory");
    __builtin_amdgcn_s_barrier();
    __builtin_amdgcn_sched_barrier(0);
    const int nb3 = (cur + 2 >= 3) ? cur - 1 : cur + 2;   // (kt+2)%3
    stage(kt + 2, nb3);
    compute_tile(kt, kld[cur], vld[cur]);
    cur = (cur + 1 >= 3) ? 0 : cur + 1;
  }
  // tail: tile 15 — only its 4 DMAs remain outstanding
  asm volatile("s_waitcnt vmcnt(0)" ::: "memory");
  __builtin_amdgcn_s_barrier();
  __builtin_amdgcn_sched_barrier(0);
  compute_tile(15, kld[cur], vld[cur]);

  // epilogue: partial O (unnormalized, bf16); row = qw+h*16+quad*4+r, col = dt*16+l16
  ushort_t* OpK = Opb + (size_t)ks * 4194304;
#pragma unroll
  for (int h = 0; h < 2; ++h)
#pragma unroll
    for (int dt = 0; dt < 16; ++dt)
#pragma unroll
      for (int r = 0; r < 4; ++r)
        OpK[((size_t)b * 2048 + qw + h * 16 + quad * 4 + r) * 256 + dt * 16 + l16] =
            f2bf(o[h][dt][r]);

  // l: reduce the 4 quad-partials (each lane summed 8 keys/tile per half)
#pragma unroll
  for (int h = 0; h < 2; ++h) {
    lrun[h] += __shfl_xor(lrun[h], 16);
    lrun[h] += __shfl_xor(lrun[h], 32);
  }
  if (quad == 0) {
    lws[ks * 16384 + b * 2048 + qw + l16] = lrun[0];
    lws[ks * 16384 + b * 2048 + qw + 16 + l16] = lrun[1];
  }
}

// ---- BN GEMM + LN + ReLU + FUSED masked pool (atomicAdd) — R5-proven ----
__global__ __launch_bounds__(256, 3) void k_gemm_bn(
    const ushort_t* __restrict__ Opb, const float* __restrict__ lws,
    const ushort_t* __restrict__ WT,
    const float* __restrict__ bia, const float* __restrict__ g,
    const float* __restrict__ beta, float* __restrict__ pooledAcc) {
  __shared__ short Al[32 * 72];
  __shared__ short Bl[128 * 72];
  __shared__ float red1[32][2], red2[32][2];
  __shared__ float sCm[32];
  const int t = threadIdx.x;
  const int wv = t >> 6, lane = t & 63, l16 = lane & 15, quad = lane >> 4;
  const int wm = wv >> 1, wn = wv & 1;
  const int row0 = blockIdx.x * 32;
  const int b = row0 >> 11;

  if (t < 32) {
    const int row = row0 + t;
    sCm[t] = 1.f / (lws[row] + lws[16384 + row] + lws[32768 + row] + lws[49152 + row]);
  }

  f4 acc[4];
#pragma unroll
  for (int nf = 0; nf < 4; ++nf) acc[nf] = (f4){0.f, 0.f, 0.f, 0.f};

  for (int k0 = 0; k0 < 256; k0 += 64) {
    __syncthreads();
    {   // stage A: sum 4 bf16 partials, scale, repack bf16
      const int r = t >> 3, c8 = t & 7;
      const float c0 = sCm[r];
      const size_t off = (size_t)(row0 + r) * 256 + k0 + c8 * 8;
      float e[8];
#pragma unroll
      for (int j = 0; j < 8; ++j) e[j] = 0.f;
#pragma unroll
      for (int pp = 0; pp < 4; ++pp) {
        const uint4 u = *(const uint4*)&Opb[(size_t)pp * 4194304 + off];
        e[0] += bf2f((ushort_t)(u.x & 0xffff)); e[1] += bf2f((ushort_t)(u.x >> 16));
        e[2] += bf2f((ushort_t)(u.y & 0xffff)); e[3] += bf2f((ushort_t)(u.y >> 16));
        e[4] += bf2f((ushort_t)(u.z & 0xffff)); e[5] += bf2f((ushort_t)(u.z >> 16));
        e[6] += bf2f((ushort_t)(u.w & 0xffff)); e[7] += bf2f((ushort_t)(u.w >> 16));
      }
      float4 ea = {c0 * e[0], c0 * e[1], c0 * e[2], c0 * e[3]};
      float4 eb = {c0 * e[4], c0 * e[5], c0 * e[6], c0 * e[7]};
      *(uint4*)&Al[r * 72 + c8 * 8] = pack8(ea, eb);
    }
#pragma unroll
    for (int i = 0; i < 4; ++i) {
      const int ch = t + i * 256;
      const int r = ch >> 3, c8 = ch & 7;
      *(uint4*)&Bl[r * 72 + c8 * 8] =
          *(const uint4*)&WT[(size_t)r * 256 + k0 + c8 * 8];
    }
    __syncthreads();
#pragma unroll
    for (int kc = 0; kc < 2; ++kc) {
      const s8 af = *(const s8*)&Al[(wm * 16 + l16) * 72 + kc * 32 + quad * 8];
#pragma unroll
      for (int nf = 0; nf < 4; ++nf) {
        const s8 bf = *(const s8*)&Bl[(wn * 64 + nf * 16 + l16) * 72 + kc * 32 + quad * 8];
        acc[nf] = __builtin_amdgcn_mfma_f32_16x16x32_bf16(af, bf, acc[nf], 0, 0, 0);
      }
    }
  }
  float bi[4], gg[4], bb[4];
#pragma unroll
  for (int nf = 0; nf < 4; ++nf) {
    const int col = wn * 64 + nf * 16 + l16;
    bi[nf] = bia[col]; gg[nf] = g[col]; bb[nf] = beta[col];
  }
  float s1[4] = {0.f, 0.f, 0.f, 0.f}, s2[4] = {0.f, 0.f, 0.f, 0.f};
#pragma unroll
  for (int nf = 0; nf < 4; ++nf)
#pragma unroll
    for (int r = 0; r < 4; ++r) {
      const float v = acc[nf][r] + bi[nf];
      acc[nf][r] = v;
      s1[r] += v; s2[r] += v * v;
    }
#pragma unroll
  for (int m = 1; m < 16; m <<= 1) {
#pragma unroll
    for (int r = 0; r < 4; ++r) {
      s1[r] += __shfl_xor(s1[r], m);
      s2[r] += __shfl_xor(s2[r], m);
    }
  }
  if (l16 == 0) {
#pragma unroll
    for (int r = 0; r < 4; ++r) {
      const int rl = wm * 16 + quad * 4 + r;
      red1[rl][wn] = s1[r]; red2[rl][wn] = s2[r];
    }
  }
  __syncthreads();
  // LN + ReLU + masked row-sum (in registers), then atomics
#pragma unroll
  for (int r = 0; r < 4; ++r) {
    const int rl = wm * 16 + quad * 4 + r;
    const float mu = (red1[rl][0] + red1[rl][1]) * (1.f / 128.f);
    const float var = (red2[rl][0] + red2[rl][1]) * (1.f / 128.f) - mu * mu;
    const float rstd = rsqrtf(var + 1e-5f);
#pragma unroll
    for (int nf = 0; nf < 4; ++nf) {
      const float v = (acc[nf][r] - mu) * rstd * gg[nf] + bb[nf];
      acc[nf][r] = fmaxf(v, 0.f);
    }
  }
  // apply row mask and sum over the 4 rows this lane owns
  {
    float mw[4];
#pragma unroll
    for (int r = 0; r < 4; ++r) {
      const int rl = wm * 16 + quad * 4 + r;
      mw[r] = pooledAcc[1024 + row0 + rl];  // mask staged as float by k_wt_all y==5
    }
#pragma unroll
    for (int nf = 0; nf < 4; ++nf) {
      float s = acc[nf][0] * mw[0] + acc[nf][1] * mw[1] +
                acc[nf][2] * mw[2] + acc[nf][3] * mw[3];
      // reduce across quads (rows): lanes quad 0..3 same l16
      s += __shfl_xor(s, 16);
      s += __shfl_xor(s, 32);
      if (quad == 0) {
        const int col = wn * 64 + nf * 16 + l16;
        atomicAdd(&pooledAcc[b * 128 + col], s);
      }
    }
  }
}

// ---------------- fused pool finalize + MLP head ----------------
__global__ __launch_bounds__(128) void k_pool2_head(
    const float* __restrict__ pooledAcc, const int* __restrict__ mask,
    const float* __restrict__ c1w, const float* __restrict__ c1b,
    const float* __restrict__ c2w, const float* __restrict__ c2b,
    float* __restrict__ dout) {
  __shared__ float ps[128];
  __shared__ float h1[64];
  __shared__ float scnt[128];
  const int b = blockIdx.x, t = threadIdx.x;
  // count unmasked rows
  float c = 0.f;
  const int* mb = mask + b * 2048 + t * 16;
#pragma unroll
  for (int j = 0; j < 16; ++j) c += mb[j] ? 0.f : 1.f;
  scnt[t] = c;
  __syncthreads();
  for (int o2 = 64; o2 > 0; o2 >>= 1) {
    if (t < o2) scnt[t] += scnt[t + o2];
    __syncthreads();
  }
  const float cnt = scnt[0];
  const float p = pooledAcc[b * 128 + t] / fmaxf(cnt, 1e-9f);
  ps[t] = p;
  dout[80 + b * 128 + t] = p;
  __syncthreads();
  if (t < 64) {
    float acc = c1b[t];
    for (int d = 0; d < 128; ++d) acc += ps[d] * c1w[d * 64 + t];
    h1[t] = fmaxf(acc, 0.f);
  }
  __syncthreads();
  if (t < 10) {
    float a2 = c2b[t];
    for (int j = 0; j < 64; ++j) a2 += h1[j] * c2w[j * 10 + t];
    dout[b * 10 + t] = a2;
  }
}

extern "C" void kernel_launch(void* const* d_in, const int* in_sizes, int n_in,
                              void* d_out, int out_size, void* d_ws, size_t ws_size,
                              hipStream_t stream) {
  const float* lf     = (const float*)d_in[0];
  const float* coords = (const float*)d_in[1];
  const int*   mask   = (const int*)d_in[2];
  const float* enc_w  = (const float*)d_in[3];
  const float* enc_b  = (const float*)d_in[4];
  const float* enc_g  = (const float*)d_in[5];
  const float* enc_be = (const float*)d_in[6];
  const float* gamma  = (const float*)d_in[7];
  const float* wq     = (const float*)d_in[8];
  const float* bq     = (const float*)d_in[9];
  const float* wk     = (const float*)d_in[10];
  const float* bk     = (const float*)d_in[11];
  const float* wv     = (const float*)d_in[12];
  const float* bv     = (const float*)d_in[13];
  const float* bn_w   = (const float*)d_in[14];
  const float* bn_b   = (const float*)d_in[15];
  const float* bn_g   = (const float*)d_in[16];
  const float* bn_be  = (const float*)d_in[17];
  const float* c1w    = (const float*)d_in[18];
  const float* c1b    = (const float*)d_in[19];
  const float* c2w    = (const float*)d_in[20];
  const float* c2b    = (const float*)d_in[21];

  // ws layout (float units):
  //  [0,2M) unused (was h_bf) | [2M,4M) q_bf | [4M,6M) k_bf | [6M,8M) vt_bf
  //  [8M,16M) Op bf16, 4 partials x 4194304 ushorts
  //  [16.8M..) enc_wT | wqkvT | bn_wT | lws(4x16K) | pooledAcc(1024)+maskf(16384)
  float* ws = (float*)d_ws;
  ushort_t* q_bf   = (ushort_t*)(ws + 2097152);
  ushort_t* k_bf   = (ushort_t*)(ws + 4194304);
  ushort_t* vt_bf  = (ushort_t*)(ws + 6291456);
  ushort_t* Opb    = (ushort_t*)(ws + 8388608);    // 4 x 4194304 ushorts
  ushort_t* enc_wT = (ushort_t*)(ws + 17825792);
  ushort_t* wqkvT  = (ushort_t*)(ws + 17891328);
  ushort_t* bn_wT  = (ushort_t*)(ws + 17989632);
  float*    lws    = ws + 18006016;                // 4 x 16384
  float*    pooledAcc = ws + 18071552;             // [0,1024) sums; [1024,17408) maskf
  float* out = (float*)d_out;

  k_wt_all<<<dim3(512, 6), 256, 0, stream>>>(enc_w, wq, wk, wv, bn_w, mask,
                                             enc_wT, wqkvT, bn_wT, pooledAcc);
  k_enc_qkv<<<512, 256, 0, stream>>>(lf, enc_wT, enc_b, enc_g, enc_be,
                                     wqkvT, bq, bk, bv, q_bf, k_bf, vt_bf);
  k_attn<<<dim3(8, 4, 8), 512, 0, stream>>>(q_bf, k_bf, vt_bf, coords, mask, gamma,
                                            Opb, lws);
  k_gemm_bn<<<512, 256, 0, stream>>>(Opb, lws, bn_wT, bn_b, bn_g, bn_be, pooledAcc);
  k_pool2_head<<<8, 128, 0, stream>>>(pooledAcc, mask, c1w, c1b, c2w, c2b, out);
}

// Round 9
// 214.158 us; speedup vs baseline: 1.0304x; 1.0304x over previous
//
#include <hip/hip_runtime.h>
#include <hip/hip_bf16.h>

typedef unsigned short ushort_t;
typedef __attribute__((ext_vector_type(8))) short s8;     // 8 bf16 (4 VGPRs)
typedef __attribute__((ext_vector_type(4))) float f4;     // 16x16 MFMA C/D

__device__ __forceinline__ unsigned short f2bf(float f) {
  union { float f; unsigned int u; } c; c.f = f;
  unsigned int r = (c.u + 0x7fffu + ((c.u >> 16) & 1u)) >> 16;
  return (unsigned short)r;
}
__device__ __forceinline__ float bf2f(ushort_t u) {
  union { unsigned int i; float f; } c; c.i = ((unsigned int)u) << 16; return c.f;
}
__device__ __forceinline__ uint4 pack8(float4 a, float4 b) {
  uint4 r;
  r.x = (unsigned)f2bf(a.x) | ((unsigned)f2bf(a.y) << 16);
  r.y = (unsigned)f2bf(a.z) | ((unsigned)f2bf(a.w) << 16);
  r.z = (unsigned)f2bf(b.x) | ((unsigned)f2bf(b.y) << 16);
  r.w = (unsigned)f2bf(b.z) | ((unsigned)f2bf(b.w) << 16);
  return r;
}
// raw v_sqrt_f32 / v_exp_f32 (~1 ulp) — avoid libm expansions
__device__ __forceinline__ float fsqrt_fast(float x) {
  float r; asm("v_sqrt_f32 %0, %1" : "=v"(r) : "v"(x)); return r;
}
__device__ __forceinline__ float fexp2_fast(float x) {
  float r; asm("v_exp_f32 %0, %1" : "=v"(r) : "v"(x)); return r;
}
// global -> LDS DMA, 16B per lane, wave-uniform LDS base + lane*16
// NOTE (R6 lesson): only profitable with coalesced lane addressing AND a
// pipeline to hide the latency (k_attn). NOT a drop-in for 2-barrier GEMMs.
// NOTE (R8 lesson): kernel fusion that drops occupancy (3/CU -> 2/CU) and
// multiplies B-staging loses more than the saved HBM round-trip + launch.
__device__ __forceinline__ void dma16(const ushort_t* g, const short* l) {
  __builtin_amdgcn_global_load_lds(
      (const __attribute__((address_space(1))) unsigned int*)g,
      (__attribute__((address_space(3))) unsigned int*)(unsigned long)l,
      16, 0, 0);
}

#define LOG2E 1.44269504f

// ---- all weight transposes + mask staging in one launch ----
// y 0..4: dst[n][k] = bf16(src[k][n]); y==5: mask -> float weights + zero acc
__global__ __launch_bounds__(256) void k_wt_all(
    const float* __restrict__ enc_w, const float* __restrict__ wq,
    const float* __restrict__ wk, const float* __restrict__ wv,
    const float* __restrict__ bn_w, const int* __restrict__ mask,
    ushort_t* __restrict__ enc_wT, ushort_t* __restrict__ wqkvT,
    ushort_t* __restrict__ bn_wT, float* __restrict__ pooledAcc) {
  const int y = blockIdx.y;
  const int i = blockIdx.x * 256 + threadIdx.x;
  if (y == 0) {
    if (i < 131072) { const int n = i >> 9, k = i & 511; enc_wT[i] = f2bf(enc_w[k * 256 + n]); }
  } else if (y <= 3) {
    if (i < 65536) {
      const int n = i >> 8, k = i & 255;
      const float* src = (y == 1) ? wq : (y == 2) ? wk : wv;
      wqkvT[(y - 1) * 65536 + i] = f2bf(src[k * 256 + n]);
    }
  } else if (y == 4) {
    if (i < 32768) { const int n = i >> 8, k = i & 255; bn_wT[i] = f2bf(bn_w[k * 128 + n]); }
  } else {
    if (i < 16384) pooledAcc[1024 + i] = mask[i] ? 0.f : 1.f;
    if (i < 1024) pooledAcc[i] = 0.f;
  }
}

// ------- encoder GEMM + LN + ReLU; 32-row blocks (grid 512) — R5-proven -------
__global__ __launch_bounds__(256, 3) void k_gemm_enc(
    const float* __restrict__ A, const ushort_t* __restrict__ WT,
    const float* __restrict__ bia, const float* __restrict__ g,
    const float* __restrict__ beta, ushort_t* __restrict__ out) {
  __shared__ short Al[32 * 72];
  __shared__ short Bl[256 * 72];
  __shared__ float red1[32][2], red2[32][2];
  const int t = threadIdx.x;
  const int wv = t >> 6, lane = t & 63, l16 = lane & 15, quad = lane >> 4;
  const int wm = wv >> 1, wn = wv & 1;
  const int row0 = blockIdx.x * 32;

  f4 acc[8];
#pragma unroll
  for (int nf = 0; nf < 8; ++nf) acc[nf] = (f4){0.f, 0.f, 0.f, 0.f};

  for (int k0 = 0; k0 < 512; k0 += 64) {
    __syncthreads();
    {
      const int r = t >> 3, c8 = t & 7;
      const float* src = &A[(size_t)(row0 + r) * 512 + k0 + c8 * 8];
      *(uint4*)&Al[r * 72 + c8 * 8] =
          pack8(*(const float4*)src, *(const float4*)(src + 4));
    }
#pragma unroll
    for (int i = 0; i < 8; ++i) {
      const int ch = t + i * 256;
      const int r = ch >> 3, c8 = ch & 7;
      *(uint4*)&Bl[r * 72 + c8 * 8] =
          *(const uint4*)&WT[(size_t)r * 512 + k0 + c8 * 8];
    }
    __syncthreads();
#pragma unroll
    for (int kc = 0; kc < 2; ++kc) {
      const s8 af = *(const s8*)&Al[(wm * 16 + l16) * 72 + kc * 32 + quad * 8];
#pragma unroll
      for (int nf = 0; nf < 8; ++nf) {
        const s8 bf = *(const s8*)&Bl[(wn * 128 + nf * 16 + l16) * 72 + kc * 32 + quad * 8];
        acc[nf] = __builtin_amdgcn_mfma_f32_16x16x32_bf16(af, bf, acc[nf], 0, 0, 0);
      }
    }
  }
  float bi[8], gg[8], bb[8];
#pragma unroll
  for (int nf = 0; nf < 8; ++nf) {
    const int col = wn * 128 + nf * 16 + l16;
    bi[nf] = bia[col]; gg[nf] = g[col]; bb[nf] = beta[col];
  }
  float s1[4] = {0.f, 0.f, 0.f, 0.f}, s2[4] = {0.f, 0.f, 0.f, 0.f};
#pragma unroll
  for (int nf = 0; nf < 8; ++nf)
#pragma unroll
    for (int r = 0; r < 4; ++r) {
      const float v = acc[nf][r] + bi[nf];
      acc[nf][r] = v;
      s1[r] += v; s2[r] += v * v;
    }
#pragma unroll
  for (int m = 1; m < 16; m <<= 1) {
#pragma unroll
    for (int r = 0; r < 4; ++r) {
      s1[r] += __shfl_xor(s1[r], m);
      s2[r] += __shfl_xor(s2[r], m);
    }
  }
  if (l16 == 0) {
#pragma unroll
    for (int r = 0; r < 4; ++r) {
      const int rl = wm * 16 + quad * 4 + r;
      red1[rl][wn] = s1[r]; red2[rl][wn] = s2[r];
    }
  }
  __syncthreads();
#pragma unroll
  for (int r = 0; r < 4; ++r) {
    const int rl = wm * 16 + quad * 4 + r;
    const float mu = (red1[rl][0] + red1[rl][1]) * (1.f / 256.f);
    const float var = (red2[rl][0] + red2[rl][1]) * (1.f / 256.f) - mu * mu;
    const float rstd = rsqrtf(var + 1e-5f);
#pragma unroll
    for (int nf = 0; nf < 8; ++nf) {
      const int col = wn * 128 + nf * 16 + l16;
      const float v = (acc[nf][r] - mu) * rstd * gg[nf] + bb[nf];
      out[(size_t)(row0 + rl) * 256 + col] = f2bf(fmaxf(v, 0.f));
    }
  }
}

// ---- QKV GEMM v3 (R7-proven): grid (256 row-blocks, 3 types) ----
// 64 rows x 256 cols/block; A re-reads 3x (24 MB). Coalesced uint4 staging
// into padded-72 LDS. q scaled log2e/16; v -> vt with the R3-proven PV key
// permutation: chunk-local key (mf*16 + quad*4 + r) -> slot (quad*8 + mf*4 + r).
__global__ __launch_bounds__(256, 3) void k_gemm_qkv(
    const ushort_t* __restrict__ A, const ushort_t* __restrict__ WT,
    const float* __restrict__ bq, const float* __restrict__ bk,
    const float* __restrict__ bv,
    ushort_t* __restrict__ q, ushort_t* __restrict__ k, ushort_t* __restrict__ vt) {
  __shared__ short Al[64 * 72];
  __shared__ short Bl[256 * 72];
  const int t = threadIdx.x;
  const int wv = t >> 6, lane = t & 63, l16 = lane & 15, quad = lane >> 4;
  const int wm = wv >> 1, wn = wv & 1;
  const int row0 = blockIdx.x * 64;
  const int type = blockIdx.y;
  const ushort_t* wtb = WT + (size_t)type * 65536;

  f4 acc[2][8];
#pragma unroll
  for (int mf = 0; mf < 2; ++mf)
#pragma unroll
    for (int nf = 0; nf < 8; ++nf) acc[mf][nf] = (f4){0.f, 0.f, 0.f, 0.f};

  for (int k0 = 0; k0 < 256; k0 += 64) {
    __syncthreads();
#pragma unroll
    for (int i = 0; i < 2; ++i) {
      const int ch = t + i * 256;
      const int r = ch >> 3, c8 = ch & 7;
      *(uint4*)&Al[r * 72 + c8 * 8] =
          *(const uint4*)&A[(size_t)(row0 + r) * 256 + k0 + c8 * 8];
    }
#pragma unroll
    for (int i = 0; i < 8; ++i) {
      const int ch = t + i * 256;
      const int r = ch >> 3, c8 = ch & 7;
      *(uint4*)&Bl[r * 72 + c8 * 8] =
          *(const uint4*)&wtb[(size_t)r * 256 + k0 + c8 * 8];
    }
    __syncthreads();
#pragma unroll
    for (int kc = 0; kc < 2; ++kc) {
      s8 af[2];
      af[0] = *(const s8*)&Al[(wm * 32 + l16) * 72 + kc * 32 + quad * 8];
      af[1] = *(const s8*)&Al[(wm * 32 + 16 + l16) * 72 + kc * 32 + quad * 8];
#pragma unroll
      for (int nf = 0; nf < 8; ++nf) {
        const s8 bf = *(const s8*)&Bl[(wn * 128 + nf * 16 + l16) * 72 + kc * 32 + quad * 8];
        acc[0][nf] = __builtin_amdgcn_mfma_f32_16x16x32_bf16(af[0], bf, acc[0][nf], 0, 0, 0);
        acc[1][nf] = __builtin_amdgcn_mfma_f32_16x16x32_bf16(af[1], bf, acc[1][nf], 0, 0, 0);
      }
    }
  }
  const float* bias = (type == 0) ? bq : (type == 1) ? bk : bv;
#pragma unroll
  for (int nf = 0; nf < 8; ++nf) {
    const int col = wn * 128 + nf * 16 + l16;
    const float bi = bias[col];
    if (type == 2) {
      const int b = row0 >> 11;
#pragma unroll
      for (int mf = 0; mf < 2; ++mf) {
        // chunk-local: hi=mf, q=quad -> permuted slot = quad*8 + mf*4 + r
        const int n = (row0 & 2047) + wm * 32 + quad * 8 + mf * 4;
        ushort4 pk;
        pk.x = f2bf(acc[mf][nf][0] + bi);
        pk.y = f2bf(acc[mf][nf][1] + bi);
        pk.z = f2bf(acc[mf][nf][2] + bi);
        pk.w = f2bf(acc[mf][nf][3] + bi);
        *(ushort4*)&vt[((size_t)b * 256 + col) * 2048 + n] = pk;
      }
    } else {
      ushort_t* dst = (type == 0) ? q : k;
      const float sc = (type == 0) ? (0.0625f * LOG2E) : 1.f;  // fold log2e for exp2
#pragma unroll
      for (int mf = 0; mf < 2; ++mf)
#pragma unroll
        for (int r = 0; r < 4; ++r) {
          const int row = row0 + wm * 32 + mf * 16 + quad * 4 + r;
          dst[(size_t)row * 256 + col] = f2bf((acc[mf][nf][r] + bi) * sc);
        }
    }
  }
}

// ---- MFMA flash attention, 8-wave / 32q-per-wave, pipelined DMA version ----
// (R5-proven structure) grid (8,4,8) = 256 blocks (1/CU), 512 thr.
// Triple-buffered LDS, DMAs 2 tiles ahead, counted s_waitcnt vmcnt(4) before
// a raw s_barrier so the next tile's DMAs stay in flight across the barrier.
// R9 addition (T5): s_setprio(1) around the QK and PV MFMA clusters — the
// counted-vmcnt pipeline phase-skews the 8 waves, so the CU scheduler can
// favor MFMA-entering waves over load/VALU-phase waves (m191 precedent).
__global__ __launch_bounds__(512, 2) void k_attn(
    const ushort_t* __restrict__ qb, const ushort_t* __restrict__ kb,
    const ushort_t* __restrict__ vtb,
    const float* __restrict__ coords, const int* __restrict__ mask,
    const float* __restrict__ gam,
    ushort_t* __restrict__ Opb, float* __restrict__ lws) {
  __shared__ short kld[3][8192];             // 3 x 16 KB, [d-group:32][key:32][8]
  __shared__ short vld[3][8192];             // 3 x 16 KB, [slot-group:4][d:256][8]
  __shared__ __align__(16) float2 cls[512];  // key coords (4 KB)
  __shared__ __align__(16) float  mls[512];  // key mask weight 0/1 (2 KB)
  const int t = threadIdx.x;
  const int wv = t >> 6, lane = t & 63, l16 = lane & 15, quad = lane >> 4;
  const int b = blockIdx.z, ks = blockIdx.y;
  const int qw = blockIdx.x * 256 + wv * 32;
  const int kbase = ks * 512;

  const ushort_t* kbb = kb + ((size_t)b * 2048 + kbase) * 256;
  const ushort_t* vbb = vtb + (size_t)b * 256 * 2048 + kbase;

  // stage tile tt into buffer ib (4 dma16/thread, issued in fixed order)
  auto stage = [&](int tt, int ib) {
    const ushort_t* kn = kbb + (size_t)tt * 8192;
    const ushort_t* vn = vbb + tt * 32;
    const int key = t & 31, dg = t >> 5;
    dma16(kn + (size_t)key * 256 + dg * 8, &kld[ib][t * 8]);
    dma16(kn + (size_t)key * 256 + dg * 8 + 128, &kld[ib][(t + 512) * 8]);
    const int d = t & 255, kg = t >> 8;
    dma16(vn + (size_t)d * 2048 + kg * 8, &vld[ib][t * 8]);
    dma16(vn + (size_t)d * 2048 + kg * 8 + 16, &vld[ib][(t + 512) * 8]);
  };

  // ---- prologue: stage tiles 0,1; stage coords/mask; load per-wave consts ----
  stage(0, 0);
  stage(1, 1);
  cls[t] = ((const float2*)coords)[b * 2048 + kbase + t];
  mls[t] = mask[b * 2048 + kbase + t] ? 0.f : 1.f;

  s8 qa[2][8];
  {
    const ushort_t* qrow = qb + ((size_t)b * 2048 + qw + l16) * 256 + quad * 8;
#pragma unroll
    for (int c = 0; c < 8; ++c) {
      qa[0][c] = *(const s8*)(qrow + c * 32);
      qa[1][c] = *(const s8*)(qrow + 16 * 256 + c * 32);
    }
  }
  float rcx[2], rcy[2];
  {
    const float2 c0 = ((const float2*)coords)[b * 2048 + qw + l16];
    const float2 c1 = ((const float2*)coords)[b * 2048 + qw + 16 + l16];
    rcx[0] = c0.x; rcy[0] = c0.y; rcx[1] = c1.x; rcy[1] = c1.y;
  }
  const float gl2 = fabsf(gam[0]) * LOG2E;

  f4 o[2][16];
#pragma unroll
  for (int h = 0; h < 2; ++h)
#pragma unroll
    for (int dt = 0; dt < 16; ++dt) o[h][dt] = (f4){0.f, 0.f, 0.f, 0.f};
  float lrun[2] = {0.f, 0.f};

  // per-tile compute on buffers kldc/vldc
  auto compute_tile = [&](int kt, const short* kldc, const short* vldc) {
    // QK^T swapped: sc[h][s] = K(s-frag) x Q(half h); each kf feeds both halves
    f4 sc[2][2];
    sc[0][0] = (f4){0.f, 0.f, 0.f, 0.f}; sc[0][1] = (f4){0.f, 0.f, 0.f, 0.f};
    sc[1][0] = (f4){0.f, 0.f, 0.f, 0.f}; sc[1][1] = (f4){0.f, 0.f, 0.f, 0.f};
    __builtin_amdgcn_s_setprio(1);
#pragma unroll
    for (int c = 0; c < 8; ++c) {
      const s8 kf0 = *(const s8*)&kldc[((c * 4 + quad) * 32 + l16) * 8];
      sc[0][0] = __builtin_amdgcn_mfma_f32_16x16x32_bf16(kf0, qa[0][c], sc[0][0], 0, 0, 0);
      sc[1][0] = __builtin_amdgcn_mfma_f32_16x16x32_bf16(kf0, qa[1][c], sc[1][0], 0, 0, 0);
      const s8 kf1 = *(const s8*)&kldc[((c * 4 + quad) * 32 + 16 + l16) * 8];
      sc[0][1] = __builtin_amdgcn_mfma_f32_16x16x32_bf16(kf1, qa[0][c], sc[0][1], 0, 0, 0);
      sc[1][1] = __builtin_amdgcn_mfma_f32_16x16x32_bf16(kf1, qa[1][c], sc[1][1], 0, 0, 0);
    }
    __builtin_amdgcn_s_setprio(0);
    // softmax weights in-register (no max-shift); coords/mask broadcast from LDS
    s8 paf[2];
#pragma unroll
    for (int h = 0; h < 2; ++h) {
      unsigned pu[4];
#pragma unroll
      for (int s = 0; s < 2; ++s) {
        const int k0 = kt * 32 + s * 16 + quad * 4;
        const float4 c01 = *(const float4*)&cls[k0];
        const float4 c23 = *(const float4*)&cls[k0 + 2];
        const float4 mm = *(const float4*)&mls[k0];
        const float kx[4] = {c01.x, c01.z, c23.x, c23.z};
        const float ky[4] = {c01.y, c01.w, c23.y, c23.w};
        const float mv[4] = {mm.x, mm.y, mm.z, mm.w};
        float w[4];
#pragma unroll
        for (int r = 0; r < 4; ++r) {
          const float p = fexp2_fast(sc[h][s][r]);   // q pre-scaled by log2e/16
          lrun[h] += p;
          const float dx = rcx[h] - kx[r], dy = rcy[h] - ky[r];
          const float dist = fsqrt_fast(dx * dx + dy * dy);
          w[r] = p * fexp2_fast(-gl2 * dist) * mv[r];
        }
        pu[s * 2 + 0] = (unsigned)f2bf(w[0]) | ((unsigned)f2bf(w[1]) << 16);
        pu[s * 2 + 1] = (unsigned)f2bf(w[2]) | ((unsigned)f2bf(w[3]) << 16);
      }
      union { s8 v; unsigned u[4]; } cv;
      cv.u[0] = pu[0]; cv.u[1] = pu[1]; cv.u[2] = pu[2]; cv.u[3] = pu[3];
      paf[h] = cv.v;
    }
    // PV (16x16x32): one aligned conflict-free b128 per dt, shared by halves
    __builtin_amdgcn_s_setprio(1);
#pragma unroll
    for (int dt = 0; dt < 16; ++dt) {
      const s8 bvf = *(const s8*)&vldc[(quad * 256 + dt * 16 + l16) * 8];
      o[0][dt] = __builtin_amdgcn_mfma_f32_16x16x32_bf16(paf[0], bvf, o[0][dt], 0, 0, 0);
      o[1][dt] = __builtin_amdgcn_mfma_f32_16x16x32_bf16(paf[1], bvf, o[1][dt], 0, 0, 0);
    }
    __builtin_amdgcn_s_setprio(0);
  };

  __syncthreads();              // full drain: tiles 0,1 + cls/mls visible
  stage(2, 2);                  // tile 2 in flight during tile 0 compute
  compute_tile(0, kld[0], vld[0]);

  int cur = 1;                  // buffer of tile kt
  for (int kt = 1; kt < 15; ++kt) {
    // tile kt's DMAs are the 4 oldest of (up to) 8 outstanding; kt+1's stay in flight
    asm volatile("s_waitcnt vmcnt(4)" ::: "memory");
    __builtin_amdgcn_s_barrier();
    __builtin_amdgcn_sched_barrier(0);
    const int nb3 = (cur + 2 >= 3) ? cur - 1 : cur + 2;   // (kt+2)%3
    stage(kt + 2, nb3);
    compute_tile(kt, kld[cur], vld[cur]);
    cur = (cur + 1 >= 3) ? 0 : cur + 1;
  }
  // tail: tile 15 — only its 4 DMAs remain outstanding
  asm volatile("s_waitcnt vmcnt(0)" ::: "memory");
  __builtin_amdgcn_s_barrier();
  __builtin_amdgcn_sched_barrier(0);
  compute_tile(15, kld[cur], vld[cur]);

  // epilogue: partial O (unnormalized, bf16); row = qw+h*16+quad*4+r, col = dt*16+l16
  ushort_t* OpK = Opb + (size_t)ks * 4194304;
#pragma unroll
  for (int h = 0; h < 2; ++h)
#pragma unroll
    for (int dt = 0; dt < 16; ++dt)
#pragma unroll
      for (int r = 0; r < 4; ++r)
        OpK[((size_t)b * 2048 + qw + h * 16 + quad * 4 + r) * 256 + dt * 16 + l16] =
            f2bf(o[h][dt][r]);

  // l: reduce the 4 quad-partials (each lane summed 8 keys/tile per half)
#pragma unroll
  for (int h = 0; h < 2; ++h) {
    lrun[h] += __shfl_xor(lrun[h], 16);
    lrun[h] += __shfl_xor(lrun[h], 32);
  }
  if (quad == 0) {
    lws[ks * 16384 + b * 2048 + qw + l16] = lrun[0];
    lws[ks * 16384 + b * 2048 + qw + 16 + l16] = lrun[1];
  }
}

// ---- BN GEMM + LN + ReLU + FUSED masked pool (atomicAdd) — R5-proven ----
__global__ __launch_bounds__(256, 3) void k_gemm_bn(
    const ushort_t* __restrict__ Opb, const float* __restrict__ lws,
    const ushort_t* __restrict__ WT,
    const float* __restrict__ bia, const float* __restrict__ g,
    const float* __restrict__ beta, float* __restrict__ pooledAcc) {
  __shared__ short Al[32 * 72];
  __shared__ short Bl[128 * 72];
  __shared__ float red1[32][2], red2[32][2];
  __shared__ float sCm[32];
  const int t = threadIdx.x;
  const int wv = t >> 6, lane = t & 63, l16 = lane & 15, quad = lane >> 4;
  const int wm = wv >> 1, wn = wv & 1;
  const int row0 = blockIdx.x * 32;
  const int b = row0 >> 11;

  if (t < 32) {
    const int row = row0 + t;
    sCm[t] = 1.f / (lws[row] + lws[16384 + row] + lws[32768 + row] + lws[49152 + row]);
  }

  f4 acc[4];
#pragma unroll
  for (int nf = 0; nf < 4; ++nf) acc[nf] = (f4){0.f, 0.f, 0.f, 0.f};

  for (int k0 = 0; k0 < 256; k0 += 64) {
    __syncthreads();
    {   // stage A: sum 4 bf16 partials, scale, repack bf16
      const int r = t >> 3, c8 = t & 7;
      const float c0 = sCm[r];
      const size_t off = (size_t)(row0 + r) * 256 + k0 + c8 * 8;
      float e[8];
#pragma unroll
      for (int j = 0; j < 8; ++j) e[j] = 0.f;
#pragma unroll
      for (int pp = 0; pp < 4; ++pp) {
        const uint4 u = *(const uint4*)&Opb[(size_t)pp * 4194304 + off];
        e[0] += bf2f((ushort_t)(u.x & 0xffff)); e[1] += bf2f((ushort_t)(u.x >> 16));
        e[2] += bf2f((ushort_t)(u.y & 0xffff)); e[3] += bf2f((ushort_t)(u.y >> 16));
        e[4] += bf2f((ushort_t)(u.z & 0xffff)); e[5] += bf2f((ushort_t)(u.z >> 16));
        e[6] += bf2f((ushort_t)(u.w & 0xffff)); e[7] += bf2f((ushort_t)(u.w >> 16));
      }
      float4 ea = {c0 * e[0], c0 * e[1], c0 * e[2], c0 * e[3]};
      float4 eb = {c0 * e[4], c0 * e[5], c0 * e[6], c0 * e[7]};
      *(uint4*)&Al[r * 72 + c8 * 8] = pack8(ea, eb);
    }
#pragma unroll
    for (int i = 0; i < 4; ++i) {
      const int ch = t + i * 256;
      const int r = ch >> 3, c8 = ch & 7;
      *(uint4*)&Bl[r * 72 + c8 * 8] =
          *(const uint4*)&WT[(size_t)r * 256 + k0 + c8 * 8];
    }
    __syncthreads();
#pragma unroll
    for (int kc = 0; kc < 2; ++kc) {
      const s8 af = *(const s8*)&Al[(wm * 16 + l16) * 72 + kc * 32 + quad * 8];
#pragma unroll
      for (int nf = 0; nf < 4; ++nf) {
        const s8 bf = *(const s8*)&Bl[(wn * 64 + nf * 16 + l16) * 72 + kc * 32 + quad * 8];
        acc[nf] = __builtin_amdgcn_mfma_f32_16x16x32_bf16(af, bf, acc[nf], 0, 0, 0);
      }
    }
  }
  float bi[4], gg[4], bb[4];
#pragma unroll
  for (int nf = 0; nf < 4; ++nf) {
    const int col = wn * 64 + nf * 16 + l16;
    bi[nf] = bia[col]; gg[nf] = g[col]; bb[nf] = beta[col];
  }
  float s1[4] = {0.f, 0.f, 0.f, 0.f}, s2[4] = {0.f, 0.f, 0.f, 0.f};
#pragma unroll
  for (int nf = 0; nf < 4; ++nf)
#pragma unroll
    for (int r = 0; r < 4; ++r) {
      const float v = acc[nf][r] + bi[nf];
      acc[nf][r] = v;
      s1[r] += v; s2[r] += v * v;
    }
#pragma unroll
  for (int m = 1; m < 16; m <<= 1) {
#pragma unroll
    for (int r = 0; r < 4; ++r) {
      s1[r] += __shfl_xor(s1[r], m);
      s2[r] += __shfl_xor(s2[r], m);
    }
  }
  if (l16 == 0) {
#pragma unroll
    for (int r = 0; r < 4; ++r) {
      const int rl = wm * 16 + quad * 4 + r;
      red1[rl][wn] = s1[r]; red2[rl][wn] = s2[r];
    }
  }
  __syncthreads();
  // LN + ReLU + masked row-sum (in registers), then atomics
#pragma unroll
  for (int r = 0; r < 4; ++r) {
    const int rl = wm * 16 + quad * 4 + r;
    const float mu = (red1[rl][0] + red1[rl][1]) * (1.f / 128.f);
    const float var = (red2[rl][0] + red2[rl][1]) * (1.f / 128.f) - mu * mu;
    const float rstd = rsqrtf(var + 1e-5f);
#pragma unroll
    for (int nf = 0; nf < 4; ++nf) {
      const float v = (acc[nf][r] - mu) * rstd * gg[nf] + bb[nf];
      acc[nf][r] = fmaxf(v, 0.f);
    }
  }
  // apply row mask and sum over the 4 rows this lane owns
  {
    float mw[4];
#pragma unroll
    for (int r = 0; r < 4; ++r) {
      const int rl = wm * 16 + quad * 4 + r;
      mw[r] = pooledAcc[1024 + row0 + rl];  // mask staged as float by k_wt_all y==5
    }
#pragma unroll
    for (int nf = 0; nf < 4; ++nf) {
      float s = acc[nf][0] * mw[0] + acc[nf][1] * mw[1] +
                acc[nf][2] * mw[2] + acc[nf][3] * mw[3];
      // reduce across quads (rows): lanes quad 0..3 same l16
      s += __shfl_xor(s, 16);
      s += __shfl_xor(s, 32);
      if (quad == 0) {
        const int col = wn * 64 + nf * 16 + l16;
        atomicAdd(&pooledAcc[b * 128 + col], s);
      }
    }
  }
}

// ---------------- fused pool finalize + MLP head ----------------
__global__ __launch_bounds__(128) void k_pool2_head(
    const float* __restrict__ pooledAcc, const int* __restrict__ mask,
    const float* __restrict__ c1w, const float* __restrict__ c1b,
    const float* __restrict__ c2w, const float* __restrict__ c2b,
    float* __restrict__ dout) {
  __shared__ float ps[128];
  __shared__ float h1[64];
  __shared__ float scnt[128];
  const int b = blockIdx.x, t = threadIdx.x;
  // count unmasked rows
  float c = 0.f;
  const int* mb = mask + b * 2048 + t * 16;
#pragma unroll
  for (int j = 0; j < 16; ++j) c += mb[j] ? 0.f : 1.f;
  scnt[t] = c;
  __syncthreads();
  for (int o2 = 64; o2 > 0; o2 >>= 1) {
    if (t < o2) scnt[t] += scnt[t + o2];
    __syncthreads();
  }
  const float cnt = scnt[0];
  const float p = pooledAcc[b * 128 + t] / fmaxf(cnt, 1e-9f);
  ps[t] = p;
  dout[80 + b * 128 + t] = p;
  __syncthreads();
  if (t < 64) {
    float acc = c1b[t];
    for (int d = 0; d < 128; ++d) acc += ps[d] * c1w[d * 64 + t];
    h1[t] = fmaxf(acc, 0.f);
  }
  __syncthreads();
  if (t < 10) {
    float a2 = c2b[t];
    for (int j = 0; j < 64; ++j) a2 += h1[j] * c2w[j * 10 + t];
    dout[b * 10 + t] = a2;
  }
}

extern "C" void kernel_launch(void* const* d_in, const int* in_sizes, int n_in,
                              void* d_out, int out_size, void* d_ws, size_t ws_size,
                              hipStream_t stream) {
  const float* lf     = (const float*)d_in[0];
  const float* coords = (const float*)d_in[1];
  const int*   mask   = (const int*)d_in[2];
  const float* enc_w  = (const float*)d_in[3];
  const float* enc_b  = (const float*)d_in[4];
  const float* enc_g  = (const float*)d_in[5];
  const float* enc_be = (const float*)d_in[6];
  const float* gamma  = (const float*)d_in[7];
  const float* wq     = (const float*)d_in[8];
  const float* bq     = (const float*)d_in[9];
  const float* wk     = (const float*)d_in[10];
  const float* bk     = (const float*)d_in[11];
  const float* wv     = (const float*)d_in[12];
  const float* bv     = (const float*)d_in[13];
  const float* bn_w   = (const float*)d_in[14];
  const float* bn_b   = (const float*)d_in[15];
  const float* bn_g   = (const float*)d_in[16];
  const float* bn_be  = (const float*)d_in[17];
  const float* c1w    = (const float*)d_in[18];
  const float* c1b    = (const float*)d_in[19];
  const float* c2w    = (const float*)d_in[20];
  const float* c2b    = (const float*)d_in[21];

  // ws layout (float units):
  //  [0,2M) h_bf | [2M,4M) q_bf | [4M,6M) k_bf | [6M,8M) vt_bf
  //  [8M,16M) Op bf16, 4 partials x 4194304 ushorts
  //  [16.8M..) enc_wT | wqkvT | bn_wT | lws(4x16K) | pooledAcc(1024)+maskf(16384)
  float* ws = (float*)d_ws;
  ushort_t* h_bf   = (ushort_t*)ws;
  ushort_t* q_bf   = (ushort_t*)(ws + 2097152);
  ushort_t* k_bf   = (ushort_t*)(ws + 4194304);
  ushort_t* vt_bf  = (ushort_t*)(ws + 6291456);
  ushort_t* Opb    = (ushort_t*)(ws + 8388608);    // 4 x 4194304 ushorts
  ushort_t* enc_wT = (ushort_t*)(ws + 17825792);
  ushort_t* wqkvT  = (ushort_t*)(ws + 17891328);
  ushort_t* bn_wT  = (ushort_t*)(ws + 17989632);
  float*    lws    = ws + 18006016;                // 4 x 16384
  float*    pooledAcc = ws + 18071552;             // [0,1024) sums; [1024,17408) maskf
  float* out = (float*)d_out;

  k_wt_all<<<dim3(512, 6), 256, 0, stream>>>(enc_w, wq, wk, wv, bn_w, mask,
                                             enc_wT, wqkvT, bn_wT, pooledAcc);
  k_gemm_enc<<<512, 256, 0, stream>>>(lf, enc_wT, enc_b, enc_g, enc_be, h_bf);
  k_gemm_qkv<<<dim3(256, 3), 256, 0, stream>>>(h_bf, wqkvT, bq, bk, bv, q_bf, k_bf, vt_bf);
  k_attn<<<dim3(8, 4, 8), 512, 0, stream>>>(q_bf, k_bf, vt_bf, coords, mask, gamma,
                                            Opb, lws);
  k_gemm_bn<<<512, 256, 0, stream>>>(Opb, lws, bn_wT, bn_b, bn_g, bn_be, pooledAcc);
  k_pool2_head<<<8, 128, 0, stream>>>(pooledAcc, mask, c1w, c1b, c2w, c2b, out);
}